// Round 3
// baseline (634.938 us; speedup 1.0000x reference)
//
#include <hip/hip_runtime.h>
#include <math.h>

// SSIM loss, (32,3,512,512) fp32, 11x11 sigma=1.5 separable Gaussian, VALID.
// R3: tile = 54x32 outputs, TI_C = 64 input cols = one wave of lanes.
//  Phase 1 (vertical): wave = 8-row strip, lane = column. 100% thread util,
//    coalesced 256B row loads, stride-1 LDS writes (one base + imm offsets).
//  Phase 2 (horizontal): thread = (row, 4-col quad). Each 16-lane quarter-wave
//    reads 16 consecutive float4s of one row (256B region) -> conflict-free
//    ds_read_b128 by construction (R2's pattern cost 83k conflict cyc/CU).
//  LDS 40KB -> 4 blocks/CU (was 48.6KB -> 3).
//  Finalize folded in via atomic ticket (saves a launch).

#define WIN   11
#define IMG   512
#define OUT_N 502
#define TO_C  54
#define TO_R  32
#define TI_C  64              // TO_C + 10, == wave width
#define GX    10              // ceil(502/54)
#define GY    16              // ceil(502/32)
#define NBLK  (GX * GY * 96)
#define C1F   6.5025f
#define C2F   58.5225f

struct GaussW { float w[WIN]; };

__global__ __launch_bounds__(256, 4) void ssim_v3_kernel(
    const float* __restrict__ X, const float* __restrict__ Y,
    GaussW gw, double* __restrict__ acc, unsigned* __restrict__ cnt,
    float* __restrict__ out)
{
    __shared__ float vb[5][TO_R][TI_C];   // 40960 B -> 4 blocks/CU
    __shared__ float wsum[4];

    const int plane = blockIdx.z;
    const int ox0 = blockIdx.x * TO_C;
    const int oy0 = blockIdx.y * TO_R;
    const float* Xp = X + (size_t)plane * IMG * IMG;
    const float* Yp = Y + (size_t)plane * IMG * IMG;
    const int tid = threadIdx.x;

    // ---- Phase 1: vertical 11-tap, wave = strip of 8 out rows, lane = col --
    {
        const int c = tid & 63;           // column within tile
        const int s = tid >> 6;           // strip id == wave id
        int gc = ox0 + c; if (gc > IMG - 1) gc = IMG - 1;
        const int r0 = oy0 + s * 8;

        float a[5][8];
#pragma unroll
        for (int f = 0; f < 5; ++f)
#pragma unroll
            for (int j = 0; j < 8; ++j) a[f][j] = 0.f;

#pragma unroll
        for (int k = 0; k < 18; ++k) {
            int gr = r0 + k; if (gr > IMG - 1) gr = IMG - 1;
            size_t off = (size_t)gr * IMG + gc;
            float x = Xp[off];
            float y = Yp[off];
            float xx = x * x, yy = y * y, xy = x * y;
            const int jlo = (k > 10) ? (k - 10) : 0;
            const int jhi = (k < 7) ? k : 7;
#pragma unroll
            for (int j = jlo; j <= jhi; ++j) {
                float wv = gw.w[k - j];
                a[0][j] += wv * x;
                a[1][j] += wv * y;
                a[2][j] += wv * xx;
                a[3][j] += wv * yy;
                a[4][j] += wv * xy;
            }
        }
#pragma unroll
        for (int f = 0; f < 5; ++f)
#pragma unroll
            for (int j = 0; j < 8; ++j)
                vb[f][s * 8 + j][c] = a[f][j];   // stride-1 across lanes
    }
    __syncthreads();

    // ---- Phase 2: horizontal 11-tap + SSIM ----
    // thread -> (row i0 and i0+16, cols c0..c0+3). Quarter-wave = 16
    // consecutive quads of one row -> conflict-free b128.
    const int t  = tid & 15;
    const int i0 = tid >> 4;              // 0..15
    const int c0 = 4 * t;                 // 0..60
    float psum = 0.f;

#pragma unroll
    for (int pass = 0; pass < 2; ++pass) {
        const int i = i0 + 16 * pass;
        const int gi = oy0 + i;
        float m[5][4];
#pragma unroll
        for (int f = 0; f < 5; ++f) {
            float v[16];
#pragma unroll
            for (int q = 0; q < 4; ++q) {
                int cq = c0 + 4 * q; if (cq > 60) cq = 60;  // clamp: feeds only masked outputs
                float4 tt = *(const float4*)&vb[f][i][cq];
                v[4 * q + 0] = tt.x; v[4 * q + 1] = tt.y;
                v[4 * q + 2] = tt.z; v[4 * q + 3] = tt.w;
            }
#pragma unroll
            for (int oc = 0; oc < 4; ++oc) {
                float s = 0.f;
#pragma unroll
                for (int k = 0; k < WIN; ++k) s += gw.w[k] * v[oc + k];
                m[f][oc] = s;
            }
        }
#pragma unroll
        for (int oc = 0; oc < 4; ++oc) {
            int lc = c0 + oc;
            int gj = ox0 + lc;
            if (lc < TO_C && gi < OUT_N && gj < OUT_N) {
                float m1 = m[0][oc], m2 = m[1][oc];
                float mu1s = m1 * m1, mu2s = m2 * m2, mu12 = m1 * m2;
                float sig1 = m[2][oc] - mu1s;
                float sig2 = m[3][oc] - mu2s;
                float sig12 = m[4][oc] - mu12;
                float cs = (2.f * sig12 + C2F) / (sig1 + sig2 + C2F);
                cs = fmaxf(cs, 0.f);
                psum += (2.f * mu12 + C1F) / (mu1s + mu2s + C1F) * cs;
            }
        }
    }

    // ---- block reduction + ticketed finalize ----
#pragma unroll
    for (int off = 32; off > 0; off >>= 1)
        psum += __shfl_down(psum, off, 64);
    if ((tid & 63) == 0) wsum[tid >> 6] = psum;
    __syncthreads();
    if (tid == 0) {
        float s = wsum[0] + wsum[1] + wsum[2] + wsum[3];
        atomicAdd(acc, (double)s);
        __threadfence();
        unsigned done = atomicAdd(cnt, 1u);
        if (done == NBLK - 1) {
            double tot = atomicAdd(acc, 0.0);   // all adds ordered before last ticket
            const double count = (double)96 * OUT_N * OUT_N;
            out[0] = (float)(1.0 - tot / count);
        }
    }
}

extern "C" void kernel_launch(void* const* d_in, const int* in_sizes, int n_in,
                              void* d_out, int out_size, void* d_ws, size_t ws_size,
                              hipStream_t stream) {
    (void)in_sizes; (void)n_in; (void)out_size; (void)ws_size;
    const float* X = (const float*)d_in[0];
    const float* Y = (const float*)d_in[1];
    float* out = (float*)d_out;
    double* acc = (double*)d_ws;
    unsigned* cnt = (unsigned*)((char*)d_ws + 8);

    hipMemsetAsync(d_ws, 0, 16, stream);

    GaussW gw;
    {
        double g[WIN], s = 0.0;
        for (int i = 0; i < WIN; ++i) {
            double d = (double)(i - 5);
            g[i] = exp(-(d * d) / (2.0 * 1.5 * 1.5));
            s += g[i];
        }
        for (int i = 0; i < WIN; ++i) gw.w[i] = (float)(g[i] / s);
    }

    dim3 grid(GX, GY, 96);
    ssim_v3_kernel<<<grid, 256, 0, stream>>>(X, Y, gw, acc, cnt, out);
}

// Round 4
// 316.428 us; speedup vs baseline: 2.0066x; 2.0066x over previous
//
#include <hip/hip_runtime.h>
#include <math.h>

// SSIM loss, (32,3,512,512) fp32, 11x11 sigma=1.5 separable Gaussian, VALID.
// R4 = R2 structure (known 173us) + one surgical change: phase-2 LDS read
// mapping switched to quarter-wave-consecutive float4 quads (16 consecutive
// lanes read 16..19 consecutive quads of one row), which measured ~2x fewer
// conflict cycles in R3. Everything else reverted from R3's regression:
// separate finalize kernel (no __threadfence ticket storm), no min-waves
// launch_bounds (VGPRs float ~80), 64-aligned column tiles.

#define WIN   11
#define IMG   512
#define OUT_N 502
#define TO_R  32              // output rows per block
#define TO_C  64              // output cols per block
#define TI_C  (TO_C + WIN - 1)   // 74 input cols
#define VB_W  76              // padded row stride, multiple of 4 (16B align)
#define C1F   6.5025f
#define C2F   58.5225f

struct GaussW { float w[WIN]; };

__global__ __launch_bounds__(256) void ssim_v4_kernel(
    const float* __restrict__ X, const float* __restrict__ Y,
    GaussW gw, double* __restrict__ acc)
{
    // vertically filtered fields: [field][out_row][col]
    __shared__ float vb[5][TO_R][VB_W];   // 48640 B -> 3 blocks/CU

    const int plane = blockIdx.z;
    const int ox0 = blockIdx.x * TO_C;    // 64-aligned global columns
    const int oy0 = blockIdx.y * TO_R;
    const float* Xp = X + (size_t)plane * IMG * IMG;
    const float* Yp = Y + (size_t)plane * IMG * IMG;
    const int tid = threadIdx.x;

    // ---- Phase 1: vertical 11-tap pass, register scatter-accumulate ----
    // 4 strips of 8 output rows x 74 cols = 296 items; lane-per-column =>
    // coalesced global loads down the column. (Imbalance: wave 0 does a 2nd
    // 40-lane round; other resident blocks absorb the slack.)
    for (int item = tid; item < 4 * TI_C; item += 256) {
        const int s = item / TI_C;          // strip 0..3
        const int c = item - s * TI_C;      // col 0..73
        int gc = ox0 + c; if (gc > IMG - 1) gc = IMG - 1;
        const int r0 = oy0 + s * 8;         // first input row of strip

        float a0[8] = {0}, a1[8] = {0}, a2[8] = {0}, a3[8] = {0}, a4[8] = {0};
#pragma unroll
        for (int k = 0; k < 18; ++k) {      // 8 outputs need 18 input rows
            int gr = r0 + k; if (gr > IMG - 1) gr = IMG - 1;
            size_t off = (size_t)gr * IMG + gc;
            float x = Xp[off];
            float y = Yp[off];
            float xx = x * x, yy = y * y, xy = x * y;
            const int jlo = (k > 10) ? (k - 10) : 0;
            const int jhi = (k < 7) ? k : 7;
#pragma unroll
            for (int j = jlo; j <= jhi; ++j) {
                float wv = gw.w[k - j];
                a0[j] += wv * x;
                a1[j] += wv * y;
                a2[j] += wv * xx;
                a3[j] += wv * yy;
                a4[j] += wv * xy;
            }
        }
#pragma unroll
        for (int j = 0; j < 8; ++j) {
            int i = s * 8 + j;
            vb[0][i][c] = a0[j];
            vb[1][i][c] = a1[j];
            vb[2][i][c] = a2[j];
            vb[3][i][c] = a3[j];
            vb[4][i][c] = a4[j];
        }
    }
    __syncthreads();

    // ---- Phase 2: horizontal 11-tap + SSIM ----
    // thread -> (rows i0, i0+16; cols 4t..4t+3). 16 consecutive lanes read
    // 16..19 consecutive float4s of one row -> near-conflict-free b128.
    const int t  = tid & 15;
    const int i0 = tid >> 4;              // 0..15
    const int c0 = 4 * t;                 // 0..60
    float psum = 0.f;

#pragma unroll
    for (int pass = 0; pass < 2; ++pass) {
        const int i = i0 + 16 * pass;
        const int gi = oy0 + i;
        float m[5][4];
#pragma unroll
        for (int f = 0; f < 5; ++f) {
            float v[16];
            const float4* p = (const float4*)&vb[f][i][c0];  // c0 mult of 4, VB_W mult of 4 -> 16B aligned
#pragma unroll
            for (int q = 0; q < 4; ++q) {       // cols c0 .. c0+15 (max 75, within VB_W pad)
                float4 tt = p[q];
                v[4 * q + 0] = tt.x; v[4 * q + 1] = tt.y;
                v[4 * q + 2] = tt.z; v[4 * q + 3] = tt.w;
            }
#pragma unroll
            for (int oc = 0; oc < 4; ++oc) {    // uses v[oc..oc+10] -> max v[13] (col 73) valid
                float s = 0.f;
#pragma unroll
                for (int k = 0; k < WIN; ++k) s += gw.w[k] * v[oc + k];
                m[f][oc] = s;
            }
        }
#pragma unroll
        for (int oc = 0; oc < 4; ++oc) {
            int gj = ox0 + c0 + oc;
            if (gi < OUT_N && gj < OUT_N) {
                float m1 = m[0][oc], m2 = m[1][oc];
                float mu1s = m1 * m1, mu2s = m2 * m2, mu12 = m1 * m2;
                float sig1 = m[2][oc] - mu1s;
                float sig2 = m[3][oc] - mu2s;
                float sig12 = m[4][oc] - mu12;
                float cs = (2.f * sig12 + C2F) / (sig1 + sig2 + C2F);
                cs = fmaxf(cs, 0.f);
                psum += (2.f * mu12 + C1F) / (mu1s + mu2s + C1F) * cs;
            }
        }
    }

    // ---- block reduction ----
#pragma unroll
    for (int off = 32; off > 0; off >>= 1)
        psum += __shfl_down(psum, off, 64);
    __shared__ float wsum[4];
    if ((tid & 63) == 0) wsum[tid >> 6] = psum;
    __syncthreads();
    if (tid == 0) {
        float s = wsum[0] + wsum[1] + wsum[2] + wsum[3];
        atomicAdd(acc, (double)s);
    }
}

__global__ void ssim_finalize_kernel(const double* __restrict__ acc,
                                     float* __restrict__ out)
{
    if (threadIdx.x == 0 && blockIdx.x == 0) {
        const double count = (double)96 * OUT_N * OUT_N;
        out[0] = (float)(1.0 - (*acc) / count);
    }
}

extern "C" void kernel_launch(void* const* d_in, const int* in_sizes, int n_in,
                              void* d_out, int out_size, void* d_ws, size_t ws_size,
                              hipStream_t stream) {
    (void)in_sizes; (void)n_in; (void)out_size; (void)ws_size;
    const float* X = (const float*)d_in[0];
    const float* Y = (const float*)d_in[1];
    float* out = (float*)d_out;
    double* acc = (double*)d_ws;

    hipMemsetAsync(d_ws, 0, sizeof(double), stream);

    GaussW gw;
    {
        double g[WIN], s = 0.0;
        for (int i = 0; i < WIN; ++i) {
            double d = (double)(i - 5);
            g[i] = exp(-(d * d) / (2.0 * 1.5 * 1.5));
            s += g[i];
        }
        for (int i = 0; i < WIN; ++i) gw.w[i] = (float)(g[i] / s);
    }

    dim3 grid((OUT_N + TO_C - 1) / TO_C,   // 8
              (OUT_N + TO_R - 1) / TO_R,   // 16
              96);
    ssim_v4_kernel<<<grid, 256, 0, stream>>>(X, Y, gw, acc);
    ssim_finalize_kernel<<<1, 64, 0, stream>>>(acc, out);
}

// Round 5
// 313.836 us; speedup vs baseline: 2.0232x; 1.0083x over previous
//
#include <hip/hip_runtime.h>
#include <math.h>

// SSIM loss, (32,3,512,512) fp32, 11x11 sigma=1.5 separable Gaussian, VALID.
// R5 = R4 structure with phase-2 LDS access rebuilt conflict-free:
//  - row stride 77 (odd): bank = (13*i + 8*t + k) mod 32; 13i distinct mod 8
//    over i=0..7, within-row only t,t+4 collide -> exact 2-way = free (m136).
//  - scalar ds_read_b32 (float4 reads on mult-of-4 strides are structurally
//    8-way conflicted: every dword phase hits banks ===0 mod 4 -- R4 evidence:
//    conflicts 32.3M).
//  - 8 outputs/thread, single pass; one vaddr + 90 immediate-offset reads.
//  - phase-1 items split contiguously per wave (balanced 74 each, no wave-0
//    double round).
//  - SSIM with one v_rcp_f32: relu folds into numerator (first factor > 0).

#define WIN   11
#define IMG   512
#define OUT_N 502
#define TO_R  32                 // output rows per block
#define TO_C  64                 // output cols per block
#define TI_C  (TO_C + WIN - 1)   // 74 input cols
#define VB_W  77                 // ODD row stride -> conflict-free scalar reads
#define C1F   6.5025f
#define C2F   58.5225f

struct GaussW { float w[WIN]; };

__global__ __launch_bounds__(256) void ssim_v5_kernel(
    const float* __restrict__ X, const float* __restrict__ Y,
    GaussW gw, double* __restrict__ acc)
{
    // vertically filtered fields: [field][out_row][col], stride 77
    __shared__ float vb[5][TO_R][VB_W];   // 49280 B -> 3 blocks/CU

    const int plane = blockIdx.z;
    const int ox0 = blockIdx.x * TO_C;    // 64-aligned global columns
    const int oy0 = blockIdx.y * TO_R;
    const float* Xp = X + (size_t)plane * IMG * IMG;
    const float* Yp = Y + (size_t)plane * IMG * IMG;
    const int tid  = threadIdx.x;
    const int wave = tid >> 6;
    const int lane = tid & 63;

    // ---- Phase 1: vertical 11-tap, register scatter-accumulate ----
    // wave w owns strip w (8 output rows x 74 cols): rounds of 64 + 10 lanes.
    {
        const int s  = wave;
        const int r0 = oy0 + s * 8;
        for (int c = lane; c < TI_C; c += 64) {
            int gc = ox0 + c; if (gc > IMG - 1) gc = IMG - 1;

            float a0[8] = {0}, a1[8] = {0}, a2[8] = {0}, a3[8] = {0}, a4[8] = {0};
#pragma unroll
            for (int k = 0; k < 18; ++k) {    // 8 outputs need 18 input rows
                int gr = r0 + k; if (gr > IMG - 1) gr = IMG - 1;
                size_t off = (size_t)gr * IMG + gc;
                float x = Xp[off];
                float y = Yp[off];
                float xx = x * x, yy = y * y, xy = x * y;
                const int jlo = (k > 10) ? (k - 10) : 0;
                const int jhi = (k < 7) ? k : 7;
#pragma unroll
                for (int j = jlo; j <= jhi; ++j) {
                    float wv = gw.w[k - j];
                    a0[j] += wv * x;
                    a1[j] += wv * y;
                    a2[j] += wv * xx;
                    a3[j] += wv * yy;
                    a4[j] += wv * xy;
                }
            }
#pragma unroll
            for (int j = 0; j < 8; ++j) {     // stride-1 across lanes: free
                int i = s * 8 + j;
                vb[0][i][c] = a0[j];
                vb[1][i][c] = a1[j];
                vb[2][i][c] = a2[j];
                vb[3][i][c] = a3[j];
                vb[4][i][c] = a4[j];
            }
        }
    }
    __syncthreads();

    // ---- Phase 2: horizontal 11-tap + SSIM, 8 outputs/thread ----
    const int i  = tid >> 3;              // 0..31
    const int c0 = (tid & 7) * 8;         // 0..56
    const int gi = oy0 + i;
    float m[5][8];
#pragma unroll
    for (int f = 0; f < 5; ++f) {
        float v[18];
#pragma unroll
        for (int k = 0; k < 18; ++k) v[k] = vb[f][i][c0 + k];  // b32, 2-way max
#pragma unroll
        for (int oc = 0; oc < 8; ++oc) {
            float s = 0.f;
#pragma unroll
            for (int k = 0; k < WIN; ++k) s += gw.w[k] * v[oc + k];
            m[f][oc] = s;
        }
    }

    float psum = 0.f;
#pragma unroll
    for (int oc = 0; oc < 8; ++oc) {
        int gj = ox0 + c0 + oc;
        if (gi < OUT_N && gj < OUT_N) {
            float m1 = m[0][oc], m2 = m[1][oc];
            float mu1s = m1 * m1, mu2s = m2 * m2, mu12 = m1 * m2;
            float sig1  = m[2][oc] - mu1s;
            float sig2  = m[3][oc] - mu2s;
            float sig12 = m[4][oc] - mu12;
            // ssim = [(2mu12+C1)/(mu1s+mu2s+C1)] * relu[(2sig12+C2)/(sig1+sig2+C2)]
            // first factor and both denominators are > 0 -> relu folds into num.
            float num = (2.f * mu12 + C1F) * (2.f * sig12 + C2F);
            float den = (mu1s + mu2s + C1F) * (sig1 + sig2 + C2F);
            num = fmaxf(num, 0.f);
            psum += num * __builtin_amdgcn_rcpf(den);
        }
    }

    // ---- block reduction ----
#pragma unroll
    for (int off = 32; off > 0; off >>= 1)
        psum += __shfl_down(psum, off, 64);
    __shared__ float wsum[4];
    if ((tid & 63) == 0) wsum[tid >> 6] = psum;
    __syncthreads();
    if (tid == 0) {
        float s = wsum[0] + wsum[1] + wsum[2] + wsum[3];
        atomicAdd(acc, (double)s);
    }
}

__global__ void ssim_finalize_kernel(const double* __restrict__ acc,
                                     float* __restrict__ out)
{
    if (threadIdx.x == 0 && blockIdx.x == 0) {
        const double count = (double)96 * OUT_N * OUT_N;
        out[0] = (float)(1.0 - (*acc) / count);
    }
}

extern "C" void kernel_launch(void* const* d_in, const int* in_sizes, int n_in,
                              void* d_out, int out_size, void* d_ws, size_t ws_size,
                              hipStream_t stream) {
    (void)in_sizes; (void)n_in; (void)out_size; (void)ws_size;
    const float* X = (const float*)d_in[0];
    const float* Y = (const float*)d_in[1];
    float* out = (float*)d_out;
    double* acc = (double*)d_ws;

    hipMemsetAsync(d_ws, 0, sizeof(double), stream);

    GaussW gw;
    {
        double g[WIN], s = 0.0;
        for (int i = 0; i < WIN; ++i) {
            double d = (double)(i - 5);
            g[i] = exp(-(d * d) / (2.0 * 1.5 * 1.5));
            s += g[i];
        }
        for (int i = 0; i < WIN; ++i) gw.w[i] = (float)(g[i] / s);
    }

    dim3 grid((OUT_N + TO_C - 1) / TO_C,   // 8
              (OUT_N + TO_R - 1) / TO_R,   // 16
              96);
    ssim_v5_kernel<<<grid, 256, 0, stream>>>(X, Y, gw, acc);
    ssim_finalize_kernel<<<1, 64, 0, stream>>>(acc, out);
}